// Round 16
// baseline (1582.138 us; speedup 1.0000x reference)
//
#include <hip/hip_runtime.h>
#include <cfloat>
#include <cmath>

// FPS: B=4, N=8192, S=1024. One block/batch; SQUARED-space min-distances in
// registers, 32 pts/thread x 256 threads (4 waves = 1/SIMD).
// LDS: float4 cloud + 12KB output buffer + 4 value slots + 2 idx words.
//
// R15 post-mortem: per-point cost ~28 instr at BOTH PPT=16 and PPT=32 =>
// no register bloat; the cost is the in-loop argmax/second-max tracking
// (cmp+2 cndmask+min+max + canonicalization). R16 deletes ALL in-loop
// tracking: update = min + paired max3 chain (~10/pt). Argmax index is
// recovered post-reduce by WINNER THREADS ONLY (R5-proven 2-barrier
// scheme): value-only DPP reduce -> slot -> tree max -> U=sqrt(M);
// threads with sqrtf(tmax)==U scan their 32 regs (exec-masked, rare),
// atomicMin the global index, barrier, broadcast.
//
// Exactness (scheme bit-exact-validated R5/R8/R13-R15): round(sqrt)
// monotone => min/max commute with sqrt. Winner check in sqrt space
// (myU==U) catches threads whose tmax differs bitwise from M but sqrt-
// collides. Fast scan: bitwise dsq==tmax (min j); near-tie detect
// (dsq>=tmax*(1-1e-6), 4x wider than the 2.4e-7 max collision gap) takes
// the exact descending sqrt scan. atomicMin over j*TPB+tid == global
// first-occurrence == jnp.argmax. Deterministic (min commutative).
//
// Races: value slots single-buffer (reads in (b1,b2); next write after
// b2). sIdx double-buffer; re-arm of sIdx[buf^1] in (b1,b2): readers of
// buf^1 finished before b1(s), next atomicMin after b2(s). Safe.

#define NPTS 8192
#define NSAMP 1024
#define TPB 256
#define PPT (NPTS / TPB)   // 32 points per thread
#define NW (TPB / 64)      // 4 waves

__device__ __forceinline__ unsigned umax2(unsigned a, unsigned b) { return a > b ? a : b; }

__global__ __launch_bounds__(TPB, 1) void fps_kernel(const float* __restrict__ pts,
                                                     float* __restrict__ out) {
#pragma clang fp contract(off)
    const int b = blockIdx.x;
    const int tid = threadIdx.x;
    const float* __restrict__ P = pts + (size_t)b * NPTS * 3;
    float* __restrict__ O = out + (size_t)b * NSAMP * 3;

    __shared__ float4 sp4[NPTS];                    // 128 KB cloud copy
    __shared__ float  sOut[NSAMP * 3];              // 12 KB selected coords
    __shared__ __align__(16) unsigned sMax[NW];     // 4 value slots (single buf)
    __shared__ unsigned sIdx[2];                    // winner index, dbuf

    float px[PPT], py[PPT], pz[PPT], dsq[PPT];

    const float p0x = P[0], p0y = P[1], p0z = P[2];
    if (tid == 0) { sIdx[0] = 0xFFFFFFFFu; sIdx[1] = 0xFFFFFFFFu; }

    // Load -> regs + LDS; dsq = ||p-p0||^2 (ref op order, contraction OFF).
    // Only a value max chain (paired -> v_max3). No index/second-max tracking.
    float tmax = 0.0f;
#pragma unroll
    for (int jj = 0; jj < PPT; jj += 2) {
        float d01[2];
#pragma unroll
        for (int k = 0; k < 2; ++k) {
            const int j = jj + k;
            const int i = j * TPB + tid;      // stride-TPB point ownership
            const float x = P[i * 3 + 0];
            const float y = P[i * 3 + 1];
            const float z = P[i * 3 + 2];
            px[j] = x; py[j] = y; pz[j] = z;
            sp4[i] = make_float4(x, y, z, 0.0f);
            const float dx = x - p0x, dy = y - p0y, dz = z - p0z;
            const float d = (dx * dx + dy * dy) + dz * dz;
            dsq[j] = d;
            d01[k] = d;
        }
        tmax = fmaxf(tmax, fmaxf(d01[0], d01[1]));   // fuses to v_max3_f32
    }
    __syncthreads();

    const int lane = tid & 63;
    const int wid  = tid >> 6;

    for (int s = 0; s < NSAMP; ++s) {
        const int buf = s & 1;

        // ---- value-only 64-lane DPP max reduce (uint order == float, >=0) ----
        unsigned v = __float_as_uint(tmax), t;
        t = (unsigned)__builtin_amdgcn_update_dpp(0, (int)v, 0x111, 0xF, 0xF, true); v = umax2(v, t);
        t = (unsigned)__builtin_amdgcn_update_dpp(0, (int)v, 0x112, 0xF, 0xF, true); v = umax2(v, t);
        t = (unsigned)__builtin_amdgcn_update_dpp(0, (int)v, 0x114, 0xF, 0xF, true); v = umax2(v, t);
        t = (unsigned)__builtin_amdgcn_update_dpp(0, (int)v, 0x118, 0xF, 0xF, true); v = umax2(v, t);
        t = (unsigned)__builtin_amdgcn_update_dpp(0, (int)v, 0x142, 0xF, 0xF, true); v = umax2(v, t);
        t = (unsigned)__builtin_amdgcn_update_dpp(0, (int)v, 0x143, 0xF, 0xF, true); v = umax2(v, t);
        if (lane == 63) sMax[wid] = v;
        __syncthreads();                      // barrier 1

        // ---- all lanes: one b128 slot read + 3-op tree -> block max M ----
        const uint4 sv = *reinterpret_cast<const uint4*>(sMax);
        const unsigned M = umax2(umax2(sv.x, sv.y), umax2(sv.z, sv.w));
        const float U   = sqrtf(__uint_as_float(M));   // reference max distance
        const float myU = sqrtf(tmax);

        if (tid == 0) sIdx[buf ^ 1] = 0xFFFFFFFFu;     // re-arm other buffer

        if (myU == U) {                        // winner thread(s) only (rare)
            unsigned cj = 0u;
            bool nt = false;
            const float thr = tmax * 0.999999f;
#pragma unroll
            for (int j = PPT - 1; j >= 0; --j) {
                nt |= (dsq[j] >= thr) & (__float_as_uint(dsq[j]) != __float_as_uint(tmax));
                if (__float_as_uint(dsq[j]) == __float_as_uint(tmax)) cj = (unsigned)j;
            }
            if (nt) {                          // exact sqrt-space scan
#pragma unroll
                for (int j = PPT - 1; j >= 0; --j)
                    if (sqrtf(dsq[j]) == U) cj = (unsigned)j;
            }
            atomicMin(&sIdx[buf], cj * TPB + (unsigned)tid);
        }
        __syncthreads();                      // barrier 2

        const int gidx = (int)sIdx[buf];      // uniform across block
        const float4 c = sp4[gidx];           // single ds_read_b128 broadcast
        const float sx = c.x, sy = c.y, sz = c.z;

        if (tid == 0) {                       // LDS, not global
            sOut[s * 3 + 0] = sx;
            sOut[s * 3 + 1] = sy;
            sOut[s * 3 + 2] = sz;
        }

        // ---- min-update, value-max only (~10 instr/pt) ----
        tmax = 0.0f;
#pragma unroll
        for (int jj = 0; jj < PPT; jj += 2) {
            float d01[2];
#pragma unroll
            for (int k = 0; k < 2; ++k) {
                const int j = jj + k;
                const float dx = px[j] - sx;
                const float dy = py[j] - sy;
                const float dz = pz[j] - sz;
                const float nd = (dx * dx + dy * dy) + dz * dz;   // contraction OFF
                const float d  = fminf(dsq[j], nd);
                dsq[j] = d;
                d01[k] = d;
            }
            tmax = fmaxf(tmax, fmaxf(d01[0], d01[1]));   // v_max3_f32
        }
    }

    // ---- epilogue: one coalesced copy LDS -> global ----
    __syncthreads();
#pragma unroll
    for (int k = tid; k < NSAMP * 3; k += TPB)
        O[k] = sOut[k];
}

extern "C" void kernel_launch(void* const* d_in, const int* in_sizes, int n_in,
                              void* d_out, int out_size, void* d_ws, size_t ws_size,
                              hipStream_t stream) {
    const float* pts = (const float*)d_in[0];
    float* out = (float*)d_out;
    const int B = in_sizes[0] / (NPTS * 3);   // 4
    fps_kernel<<<B, TPB, 0, stream>>>(pts, out);
}

// Round 17
// 1376.497 us; speedup vs baseline: 1.1494x; 1.1494x over previous
//
#include <hip/hip_runtime.h>
#include <cfloat>
#include <cmath>

// FPS: B=4, N=8192, S=1024. One block/batch; SQUARED-space min-distances in
// registers, 32 pts/thread x 256 threads (4 waves = 1/SIMD).
// LDS: float4 cloud + 12KB output buffer + 4 u64-key slots (dbuf).
//
// R16 post-mortem: winner-only post-barrier recovery added ~1400 cyc of
// serial chain (slot->U->divergent scan->atomicMin->barrier2->idx->coords)
// while saving only ~400 issue cyc => 1.4x regression. Lesson (twice now):
// index recovery must stay PRE-barrier; critical path = barrier chain.
// R17 = R15's proven 1-barrier u64-key structure + R16's cheap update loop
// (min + v_max3 chain, ~10 instr/pt) + post-loop register scan (~4/pt,
// wave-parallel, pre-barrier) replacing the 18/pt in-loop tracking.
//
// Exactness (validated R5/R8/R13-R16, all bit-exact): round(sqrt) monotone
// => min/max commute with sqrt. fmax chain returns a bitwise element of the
// set (all dsq >= +0), so the bitwise ==tmax scan finds the thread's first
// max occurrence; near-tie (any dsq in [tmax*(1-1e-6), tmax) -- 4x wider
// than the 2.4e-7 max sqrt-collision gap) takes the exact descending
// sqrt-space scan. Key = (sqrtf(tmax)_bits<<32)|~gidx: block max-key ==
// (max ds, then min index) == jnp.argmax first-occurrence. bound_ctrl
// zero-key loses to any real key. Deterministic -> tripwire-safe.
//
// Slot race: write sSlot[s&1] pre-barrier(s), read post-barrier(s); next
// write pre-barrier(s+2), separated from the read by barrier(s+1). Safe.

#define NPTS 8192
#define NSAMP 1024
#define TPB 256
#define PPT (NPTS / TPB)   // 32 points per thread
#define NW (TPB / 64)      // 4 waves

#define KEY_MERGE(CTRL)                                                               \
    do {                                                                              \
        const unsigned th = (unsigned)__builtin_amdgcn_update_dpp(0, (int)kh, (CTRL), 0xF, 0xF, true); \
        const unsigned tl = (unsigned)__builtin_amdgcn_update_dpp(0, (int)kl, (CTRL), 0xF, 0xF, true); \
        const unsigned long long tk = ((unsigned long long)th << 32) | tl;            \
        const unsigned long long pk = ((unsigned long long)kh << 32) | kl;            \
        const bool take = tk > pk;                                                    \
        kh = take ? th : kh;                                                          \
        kl = take ? tl : kl;                                                          \
    } while (0)

__global__ __launch_bounds__(TPB, 1) void fps_kernel(const float* __restrict__ pts,
                                                     float* __restrict__ out) {
#pragma clang fp contract(off)
    const int b = blockIdx.x;
    const int tid = threadIdx.x;
    const float* __restrict__ P = pts + (size_t)b * NPTS * 3;
    float* __restrict__ O = out + (size_t)b * NSAMP * 3;

    __shared__ float4 sp4[NPTS];                    // 128 KB cloud copy
    __shared__ float  sOut[NSAMP * 3];              // 12 KB selected coords
    __shared__ __align__(16) uint2 sSlot[2][NW];    // 4 key slots, dbuf

    float px[PPT], py[PPT], pz[PPT], dsq[PPT];

    const float p0x = P[0], p0y = P[1], p0z = P[2];

    // Load -> regs + LDS; dsq = ||p-p0||^2 (ref op order, contraction OFF).
    // Value-max chain only (pairs -> v_max3); no in-loop index tracking.
    float tmax = 0.0f;
#pragma unroll
    for (int jj = 0; jj < PPT; jj += 2) {
        float d01[2];
#pragma unroll
        for (int k = 0; k < 2; ++k) {
            const int j = jj + k;
            const int i = j * TPB + tid;      // stride-TPB point ownership
            const float x = P[i * 3 + 0];
            const float y = P[i * 3 + 1];
            const float z = P[i * 3 + 2];
            px[j] = x; py[j] = y; pz[j] = z;
            sp4[i] = make_float4(x, y, z, 0.0f);
            const float dx = x - p0x, dy = y - p0y, dz = z - p0z;
            const float d = (dx * dx + dy * dy) + dz * dz;
            dsq[j] = d;
            d01[k] = d;
        }
        tmax = fmaxf(tmax, fmaxf(d01[0], d01[1]));
    }
    __syncthreads();

    const int lane = tid & 63;
    const int wid  = tid >> 6;

    for (int s = 0; s < NSAMP; ++s) {
        const int buf = s & 1;

        // ---- post-loop scan (pre-barrier, all threads): min-j of max ----
        unsigned cj = 0u;
        bool nt = false;
        const float thr = tmax * 0.999999f;
#pragma unroll
        for (int j = PPT - 1; j >= 0; --j) {
            nt |= (dsq[j] >= thr) & (__float_as_uint(dsq[j]) != __float_as_uint(tmax));
            if (__float_as_uint(dsq[j]) == __float_as_uint(tmax)) cj = (unsigned)j;
        }
        const float sU = sqrtf(tmax);
        if (nt) {                             // rare exact sqrt-space path
#pragma unroll
            for (int j = PPT - 1; j >= 0; --j)
                if (sqrtf(dsq[j]) == sU) cj = (unsigned)j;
        }
        unsigned kh = __float_as_uint(sU);
        unsigned kl = ~(cj * TPB + (unsigned)tid);

        // ---- 64-lane u64-key DPP reduce -> lane 63 ----
        KEY_MERGE(0x111);   // row_shr:1
        KEY_MERGE(0x112);   // row_shr:2
        KEY_MERGE(0x114);   // row_shr:4
        KEY_MERGE(0x118);   // row_shr:8
        KEY_MERGE(0x142);   // row_bcast:15
        KEY_MERGE(0x143);   // row_bcast:31
        if (lane == 63) sSlot[buf][wid] = make_uint2(kl, kh);
        __syncthreads();                      // the ONE barrier

        // ---- all lanes: 2x b128 slot read, register u64 tree ----
        const uint4* sl = reinterpret_cast<const uint4*>(&sSlot[buf][0]);
        const uint4 a  = sl[0];               // slots 0,1
        const uint4 c4 = sl[1];               // slots 2,3
        const unsigned long long K0 = ((unsigned long long)a.y  << 32) | a.x;
        const unsigned long long K1 = ((unsigned long long)a.w  << 32) | a.z;
        const unsigned long long K2 = ((unsigned long long)c4.y << 32) | c4.x;
        const unsigned long long K3 = ((unsigned long long)c4.w << 32) | c4.z;
        const unsigned long long m01 = K0 > K1 ? K0 : K1;
        const unsigned long long m23 = K2 > K3 ? K2 : K3;
        const unsigned long long K   = m01 > m23 ? m01 : m23;

        const int gidx = (int)(~(unsigned)K); // uniform across block
        const float4 c = sp4[gidx];           // single ds_read_b128 broadcast
        const float sx = c.x, sy = c.y, sz = c.z;

        if (tid == 0) {                       // LDS, not global
            sOut[s * 3 + 0] = sx;
            sOut[s * 3 + 1] = sy;
            sOut[s * 3 + 2] = sz;
        }

        // ---- min-update, value-max only (~10 instr/pt) ----
        tmax = 0.0f;
#pragma unroll
        for (int jj = 0; jj < PPT; jj += 2) {
            float d01[2];
#pragma unroll
            for (int k = 0; k < 2; ++k) {
                const int j = jj + k;
                const float dx = px[j] - sx;
                const float dy = py[j] - sy;
                const float dz = pz[j] - sz;
                const float nd = (dx * dx + dy * dy) + dz * dz;   // contraction OFF
                const float d  = fminf(dsq[j], nd);
                dsq[j] = d;
                d01[k] = d;
            }
            tmax = fmaxf(tmax, fmaxf(d01[0], d01[1]));   // v_max3_f32
        }
    }

    // ---- epilogue: one coalesced copy LDS -> global ----
    __syncthreads();
#pragma unroll
    for (int k = tid; k < NSAMP * 3; k += TPB)
        O[k] = sOut[k];
}

extern "C" void kernel_launch(void* const* d_in, const int* in_sizes, int n_in,
                              void* d_out, int out_size, void* d_ws, size_t ws_size,
                              hipStream_t stream) {
    const float* pts = (const float*)d_in[0];
    float* out = (float*)d_out;
    const int B = in_sizes[0] / (NPTS * 3);   // 4
    fps_kernel<<<B, TPB, 0, stream>>>(pts, out);
}